// Round 5
// baseline (431.909 us; speedup 1.0000x reference)
//
#include <hip/hip_runtime.h>
#include <stdint.h>

// ContextPeftAdaptorLora on MI355X.
// Strategy: fold the 4 rank-16 LoRA adaptors into the K dimension of the base
// GEMM:  out = [x | mask*H] @ [W | 2*Bw]^T + b   with K' = 2048 + 64 = 2112.
// Pass1a: convert x->bf16 into Xaug AND compute PARTIAL H = x @ A^T (MFMA),
//         K split 4 ways -> 1024 blocks (4/CU).
// Pass1b: reduce the 4 partials, apply per-adaptor mask, write Xaug H cols.
// Pass2:  convert W->bf16 and scaled Bw into Waug.
// Pass3:  m201-style 8-phase 256x256 GEMM (the verified 1563-TF template):
//         8 waves (2Mx4N), per-wave 128x64, BK=64. Each K-tile = 4 phases =
//         4 C-quadrants (Gray order Q00,Q01,Q11,Q10); per phase:
//         ds_read frags -> stage ONE half-tile -> barrier -> lgkmcnt(0) ->
//         setprio(1) 16 MFMA setprio(0) -> barrier. ONE vmcnt(4) gate per
//         K-tile (2 stages always in flight; never vmcnt(0) in steady state).
//         Stage order per tile t: B0(t+1), A1(t+1), A0(t+2), B1(t+2) --
//         retire-order + alias-safety hand-checked. Half-tiles [128][64] bf16
//         with 8-chunk XOR swizzle on the global source (0 conflicts
//         measured in round 4). T1 XCD swizzle.

typedef __attribute__((ext_vector_type(8))) short bf16x8;   // 8 bf16 = 4 VGPR
typedef __attribute__((ext_vector_type(4))) float f32x4;    // MFMA C/D
typedef __attribute__((ext_vector_type(4))) unsigned short u16x4;
typedef __attribute__((ext_vector_type(8))) unsigned short u16x8;

#define GAS __attribute__((address_space(1)))
#define LAS __attribute__((address_space(3)))

static constexpr int BB   = 4;
static constexpr int SS   = 4096;
static constexpr int DIN  = 2048;
static constexpr int DOUT = 2048;
static constexpr int NADP = 4;
static constexpr int RR   = 16;
static constexpr int M    = BB * SS;          // 16384 rows
static constexpr int KA   = DIN + NADP * RR;  // 2112 augmented K
static constexpr float SCALE = 2.0f;          // lora_alpha / r

static constexpr int KSPLIT = 4;              // H K-reduction split factor
static constexpr int KCH    = DIN / KSPLIT;   // 512 K per block

static constexpr int NT = KA / 64;            // 33 K-tiles in the GEMM
static constexpr int HT = 128 * 64;           // ushorts per half-tile (16 KB)

static_assert(KA % 64 == 0, "K-loop needs BK=64 divisibility");
static_assert(NT >= 3, "pipeline tail assumes >=3 K-tiles");

__device__ __forceinline__ unsigned short f2bf(float f) {
  union { float f; uint32_t u; } v; v.f = f;
  uint32_t u = v.u;
  // round-to-nearest-even
  return (unsigned short)((u + 0x7FFFu + ((u >> 16) & 1u)) >> 16);
}

// ---------------------------------------------------------------------------
// Pass 1a: rows in blocks of 64, K in blocks of 512 (KSPLIT=4). Streams its
// x panel once: converts to bf16 (written to Xaug cols [kBase,kBase+512)) and
// accumulates partial H = x @ A_flat^T over its K slice via 16x16x32 bf16
// MFMA on staged LDS chunks. Epilogue writes f32 partials to Hpart[ks][M][64].
// ---------------------------------------------------------------------------
__global__ __launch_bounds__(256) void pass1a_conv_hpart(
    const float* __restrict__ x, const float* __restrict__ A,
    unsigned short* __restrict__ Xaug, float* __restrict__ Hpart)
{
  __shared__ unsigned short xb[64 * 64];  // [row][k] bf16, 8 KB
  __shared__ unsigned short ab[64 * 64];  // [j][k]   bf16, 8 KB

  const int tid = threadIdx.x;
  const int rb = blockIdx.x >> 2;         // 0..255 row-block
  const int ks = blockIdx.x & 3;          // 0..3   K-slice
  const int rowBase = rb * 64;
  const int kBase = ks * KCH;
  const int w = tid >> 6, lane = tid & 63;
  const int quad = lane >> 4, m16 = lane & 15;

  f32x4 acc[4];
  #pragma unroll
  for (int j = 0; j < 4; ++j) acc[j] = f32x4{0.f, 0.f, 0.f, 0.f};

  for (int kc = kBase; kc < kBase + KCH; kc += 64) {
    __syncthreads();  // protect LDS against overwrite while prior MFMA reads run
    #pragma unroll
    for (int l = 0; l < 4; ++l) {
      int v = l * 256 + tid;        // float4-chunk id, 0..1023
      int r = v >> 4;               // row (0..63)
      int k = (v & 15) * 4;         // k offset (0..60)
      float4 xv = *(const float4*)(x + (size_t)(rowBase + r) * DIN + kc + k);
      u16x4 xq = { f2bf(xv.x), f2bf(xv.y), f2bf(xv.z), f2bf(xv.w) };
      *(u16x4*)(xb + r * 64 + k) = xq;
      *(u16x4*)(Xaug + (size_t)(rowBase + r) * KA + kc + k) = xq;
      float4 av = *(const float4*)(A + (size_t)r * DIN + kc + k);  // j = r
      u16x4 aq = { f2bf(av.x), f2bf(av.y), f2bf(av.z), f2bf(av.w) };
      *(u16x4*)(ab + r * 64 + k) = aq;
    }
    __syncthreads();
    // wave w computes H rows [w*16, w*16+16) x all 64 j
    #pragma unroll
    for (int s = 0; s < 2; ++s) {
      bf16x8 af = *(const bf16x8*)(xb + (w * 16 + m16) * 64 + s * 32 + quad * 8);
      #pragma unroll
      for (int jt = 0; jt < 4; ++jt) {
        bf16x8 bfg = *(const bf16x8*)(ab + (jt * 16 + m16) * 64 + s * 32 + quad * 8);
        acc[jt] = __builtin_amdgcn_mfma_f32_16x16x32_bf16(af, bfg, acc[jt], 0, 0, 0);
      }
    }
  }

  // Epilogue: Hpart[ks][row][j] = partial H over this K slice.
  // C/D layout: col = lane&15, row = quad*4 + reg  [m89/m91 verified]
  const int grow0 = rowBase + w * 16 + quad * 4;
  #pragma unroll
  for (int jt = 0; jt < 4; ++jt) {
    #pragma unroll
    for (int r = 0; r < 4; ++r) {
      int grow = grow0 + r;
      Hpart[(((size_t)ks * M + grow) << 6) + jt * 16 + m16] = acc[jt][r];
    }
  }
}

// ---------------------------------------------------------------------------
// Pass 1b: H[row,j] = sum_ks Hpart[ks][row][j]; apply mask[n=j/16, row];
// write bf16 into Xaug cols [2048, 2112). ~17 MB read, 2 MB write.
// ---------------------------------------------------------------------------
__global__ __launch_bounds__(256) void pass1b_reduce_mask(
    const float* __restrict__ Hpart, const float* __restrict__ mask,
    unsigned short* __restrict__ Xaug)
{
  const int idx = blockIdx.x * 256 + threadIdx.x;  // 0 .. M*64-1
  const int row = idx >> 6;
  const int j   = idx & 63;
  float s = 0.f;
  #pragma unroll
  for (int ks = 0; ks < KSPLIT; ++ks)
    s += Hpart[(((size_t)ks * M) << 6) + idx];
  s *= mask[(size_t)(j >> 4) * M + row];
  Xaug[(size_t)row * KA + DIN + j] = f2bf(s);
}

// ---------------------------------------------------------------------------
// Pass 2: Waug[col, 0:2048) = bf16(W[col,:]);  Waug[col, 2048+n*16+r] =
// bf16(SCALE * Bw[n, col, r]).
// ---------------------------------------------------------------------------
__global__ __launch_bounds__(256) void pass2_wcvt(
    const float* __restrict__ W, const float* __restrict__ Bw,
    unsigned short* __restrict__ Waug)
{
  const int idx = blockIdx.x * 256 + threadIdx.x;  // 0..524287
  const int row = idx >> 8;          // 2048 rows, 256 8-elem chunks each
  const int k   = (idx & 255) * 8;
  float4 a = *(const float4*)(W + (size_t)row * DIN + k);
  float4 b = *(const float4*)(W + (size_t)row * DIN + k + 4);
  u16x8 q = { f2bf(a.x), f2bf(a.y), f2bf(a.z), f2bf(a.w),
              f2bf(b.x), f2bf(b.y), f2bf(b.z), f2bf(b.w) };
  *(u16x8*)(Waug + (size_t)row * KA + k) = q;

  if (idx < DOUT * NADP) {           // 8192 threads build the Bwcat columns
    const int col = idx >> 2, n = idx & 3;
    const float* src = Bw + (size_t)n * DOUT * RR + (size_t)col * RR;
    #pragma unroll
    for (int t = 0; t < 4; ++t) {
      float4 bv = *(const float4*)(src + 4 * t);
      u16x4 qq = { f2bf(SCALE * bv.x), f2bf(SCALE * bv.y),
                   f2bf(SCALE * bv.z), f2bf(SCALE * bv.w) };
      *(u16x4*)(Waug + (size_t)col * KA + DIN + n * 16 + 4 * t) = qq;
    }
  }
}

// ---------------------------------------------------------------------------
// GEMM helpers.
// ---------------------------------------------------------------------------
struct Stg { int so, dofs; };  // per-thread stage offsets (ushorts)

__device__ __forceinline__ void bar() {
  __builtin_amdgcn_sched_barrier(0);
  __builtin_amdgcn_s_barrier();
  __builtin_amdgcn_sched_barrier(0);
}
__device__ __forceinline__ void lgkm0() {
  asm volatile("s_waitcnt lgkmcnt(0)" ::: "memory");
  __builtin_amdgcn_sched_barrier(0);   // rule #18: pin MFMA after the wait
}

// Stage one half-tile (128 rows x 64 K bf16 = 16 KB) via 2 global_load_lds
// width=16 per thread (chunks tid and 512+tid). LDS dest linear (wave-uniform
// base + lane*16); chunk XOR swizzle (LDS chunk (r,cl) holds global chunk
// cl^(r&7)) applied on the GLOBAL source address. 2 vmcnt units per call.
__device__ __forceinline__ void stage_half(
    const unsigned short* __restrict__ g, unsigned short* l, int koff,
    const Stg& st)
{
  __builtin_amdgcn_global_load_lds((const GAS void*)(g + st.so + koff),
                                   (LAS void*)(l + st.dofs), 16, 0, 0);
  __builtin_amdgcn_global_load_lds((const GAS void*)(g + st.so + 64 * KA + koff),
                                   (LAS void*)(l + st.dofs + 4096), 16, 0, 0);
}

// One K-tile (BK=64) = 4 phases = 4 C-quadrants, Gray order Q00,Q01,Q11,Q10.
// Per phase: ds_read the changed operand's fragments; stage one half-tile;
// barrier; lgkmcnt(0); setprio(1); 16 MFMA; setprio(0); barrier.
// Stage order: G0: B0(t+1), G1: A1(t+1), G2: A0(t+2), G3: B1(t+2).
// Gate: ONE vmcnt(4) per K-tile before G3's closing barrier -> floats exactly
// {A0(t+2), B1(t+2)}; retires {B0(t+1), A1(t+1)} + everything older, so all
// of tile t+1 is resident entering the next group. Floating writes target
// buffers (parity t&1 A0 / B1) that nobody reads during their flight window.
// Alias-safety: each stage overwrites a buffer whose last ds_read was >=1
// barrier earlier (A0(t) last read G0, B1(t) G1, A1(t-1) prev-G2, B0(t-1)
// prev-G3). Tail: VM=0 at t=NT-2 (stages for NT..NT+1 skipped), VM=-1 last.
template<int VM, bool S01, bool S23>
__device__ __forceinline__ void kstep(int t,
    const unsigned short* __restrict__ ga, const unsigned short* __restrict__ gb,
    unsigned short* la, unsigned short* lb, const Stg& st,
    int rowA, int rowB, const int (&cc)[2], f32x4 (&acc)[8][4])
{
  const int cp = (t & 1) * (2 * HT);
  const int np = cp ^ (2 * HT);
  const unsigned short* A0 = la + cp;       // A ih=0, tile t
  const unsigned short* A1 = la + cp + HT;  // A ih=1
  const unsigned short* B0 = lb + cp;       // B jh=0
  const unsigned short* B1 = lb + cp + HT;  // B jh=1
  bf16x8 af[4][2], b[2][2];

  // ---- G0: Q(0,0) -- read A0,B0 (12); stage B0(t+1) ----
  #pragma unroll
  for (int i = 0; i < 4; ++i)
    #pragma unroll
    for (int kk = 0; kk < 2; ++kk)
      af[i][kk] = *(const bf16x8*)(A0 + rowA + i * 1024 + cc[kk]);
  #pragma unroll
  for (int j = 0; j < 2; ++j)
    #pragma unroll
    for (int kk = 0; kk < 2; ++kk)
      b[j][kk] = *(const bf16x8*)(B0 + rowB + j * 1024 + cc[kk]);
  if (S01) stage_half(gb, lb + np, (t + 1) * 64, st);
  bar(); lgkm0();
  __builtin_amdgcn_s_setprio(1);
  #pragma unroll
  for (int kk = 0; kk < 2; ++kk)
    #pragma unroll
    for (int i = 0; i < 4; ++i)
      #pragma unroll
      for (int j = 0; j < 2; ++j)
        acc[i][j] = __builtin_amdgcn_mfma_f32_16x16x32_bf16(af[i][kk], b[j][kk], acc[i][j], 0, 0, 0);
  __builtin_amdgcn_s_setprio(0);
  bar();

  // ---- G1: Q(0,1) -- read B1 (4), af held; stage A1(t+1) ----
  #pragma unroll
  for (int j = 0; j < 2; ++j)
    #pragma unroll
    for (int kk = 0; kk < 2; ++kk)
      b[j][kk] = *(const bf16x8*)(B1 + rowB + j * 1024 + cc[kk]);
  if (S01) stage_half(ga + 128 * KA, la + np + HT, (t + 1) * 64, st);
  bar(); lgkm0();
  __builtin_amdgcn_s_setprio(1);
  #pragma unroll
  for (int kk = 0; kk < 2; ++kk)
    #pragma unroll
    for (int i = 0; i < 4; ++i)
      #pragma unroll
      for (int j = 0; j < 2; ++j)
        acc[i][2 + j] = __builtin_amdgcn_mfma_f32_16x16x32_bf16(af[i][kk], b[j][kk], acc[i][2 + j], 0, 0, 0);
  __builtin_amdgcn_s_setprio(0);
  bar();

  // ---- G2: Q(1,1) -- read A1 (8), b holds B1; stage A0(t+2) ----
  #pragma unroll
  for (int i = 0; i < 4; ++i)
    #pragma unroll
    for (int kk = 0; kk < 2; ++kk)
      af[i][kk] = *(const bf16x8*)(A1 + rowA + i * 1024 + cc[kk]);
  if (S23) stage_half(ga, la + cp, (t + 2) * 64, st);
  bar(); lgkm0();
  __builtin_amdgcn_s_setprio(1);
  #pragma unroll
  for (int kk = 0; kk < 2; ++kk)
    #pragma unroll
    for (int i = 0; i < 4; ++i)
      #pragma unroll
      for (int j = 0; j < 2; ++j)
        acc[4 + i][2 + j] = __builtin_amdgcn_mfma_f32_16x16x32_bf16(af[i][kk], b[j][kk], acc[4 + i][2 + j], 0, 0, 0);
  __builtin_amdgcn_s_setprio(0);
  bar();

  // ---- G3: Q(1,0) -- re-read B0 (4), af holds A1; stage B1(t+2); GATE ----
  #pragma unroll
  for (int j = 0; j < 2; ++j)
    #pragma unroll
    for (int kk = 0; kk < 2; ++kk)
      b[j][kk] = *(const bf16x8*)(B0 + rowB + j * 1024 + cc[kk]);
  if (S23) stage_half(gb + 128 * KA, lb + cp + HT, (t + 2) * 64, st);
  bar(); lgkm0();
  __builtin_amdgcn_s_setprio(1);
  #pragma unroll
  for (int kk = 0; kk < 2; ++kk)
    #pragma unroll
    for (int i = 0; i < 4; ++i)
      #pragma unroll
      for (int j = 0; j < 2; ++j)
        acc[4 + i][j] = __builtin_amdgcn_mfma_f32_16x16x32_bf16(af[i][kk], b[j][kk], acc[4 + i][j], 0, 0, 0);
  __builtin_amdgcn_s_setprio(0);
  if constexpr (VM >= 0)
    asm volatile("s_waitcnt vmcnt(%0)" :: "i"(VM) : "memory");
  bar();
}

// ---------------------------------------------------------------------------
// Pass 3: bf16 GEMM, out[M, DOUT] = Xaug @ Waug^T + b.
// BM=BN=256, BK=64, 512 threads = 8 waves (2 wm x 4 wn). Wave output 128x64
// interleaved: rows ih*128 + wm*64 + i*16, cols jh*128 + wn*32 + j*16.
// LDS: 2 parity x 2 half x [128][64] bf16 per operand = 64 KB x2 = 128 KB.
// ---------------------------------------------------------------------------
__global__ __launch_bounds__(512, 2) void gemm_aug(
    const unsigned short* __restrict__ Xa, const unsigned short* __restrict__ Wa,
    const float* __restrict__ bias, float* __restrict__ out)
{
  __shared__ unsigned short lds_a[4 * HT];  // 64 KB
  __shared__ unsigned short lds_b[4 * HT];  // 64 KB

  const int tid = threadIdx.x;
  // T1: bijective XCD swizzle (512 wgs % 8 == 0). XCD x gets bm in
  // [x*8, x*8+8) x all 8 bn (bn fastest -> B panels reused across bm rows).
  const int lin = ((int)blockIdx.x & 7) * 64 + ((int)blockIdx.x >> 3);
  const int bm = lin >> 3, bn = lin & 7;
  const int w = tid >> 6, lane = tid & 63;
  const int wm = w >> 2, wn = w & 3;          // 2x4 wave grid
  const int quad = lane >> 4, m16 = lane & 15;

  f32x4 acc[8][4];
  #pragma unroll
  for (int i = 0; i < 8; ++i)
    #pragma unroll
    for (int j = 0; j < 4; ++j) acc[i][j] = f32x4{0.f, 0.f, 0.f, 0.f};

  const unsigned short* ga = Xa + (size_t)bm * 256 * KA;
  const unsigned short* gb = Wa + (size_t)bn * 256 * KA;

  // staging offsets: thread covers 16B chunks p=tid and p=512+tid of a
  // 128x8-chunk half-tile; chunk p1 is chunk p0 + 64 rows (same swizzle).
  Stg st;
  {
    int r = tid >> 3, c = (tid & 7) ^ (r & 7);
    st.so   = r * KA + c * 8;            // + koff (+64*KA for second load)
    st.dofs = (tid & ~63) * 8;           // wave-uniform LDS base (ushorts)
  }

  // fragment read bases; read chunk (kk*4+quad)^(m16&7) -> 2-way only (free)
  int cc[2];
  cc[0] = (quad ^ (m16 & 7)) * 8;
  cc[1] = ((4 + quad) ^ (m16 & 7)) * 8;
  const int rowA = (wm * 64 + m16) * 64;  // + i*1024 (+HT for ih=1)
  const int rowB = (wn * 32 + m16) * 64;  // + j*1024 (+HT for jh=1)

  // prologue: stage tile 0 fully + A0(1),B1(1) (the two halves g(-1).G2/G3
  // would have staged); vmcnt(4) floats exactly {A0(1),B1(1)} -> tile 0
  // resident; steady-state invariant holds entering group 0.
  stage_half(ga, lds_a, 0, st);                      // A0(0)
  stage_half(gb, lds_b, 0, st);                      // B0(0)
  stage_half(gb + 128 * KA, lds_b + HT, 0, st);      // B1(0)
  stage_half(ga + 128 * KA, lds_a + HT, 0, st);      // A1(0)
  stage_half(ga, lds_a + 2 * HT, 64, st);            // A0(1) -> parity 1
  stage_half(gb + 128 * KA, lds_b + 3 * HT, 64, st); // B1(1) -> parity 1
  asm volatile("s_waitcnt vmcnt(4)" ::: "memory");
  bar();

  for (int t = 0; t < NT - 2; ++t)
    kstep<4, true, true>(t, ga, gb, lds_a, lds_b, st, rowA, rowB, cc, acc);
  kstep<0, true, false>(NT - 2, ga, gb, lds_a, lds_b, st, rowA, rowB, cc, acc);
  kstep<-1, false, false>(NT - 1, ga, gb, lds_a, lds_b, st, rowA, rowB, cc, acc);

  // Epilogue: C/D layout col = lane&15, row = quad*4 + reg.
  // acc[ih*4+i][jh*2+j] -> row = bm*256 + ih*128 + wm*64 + i*16 + quad*4,
  //                        col = bn*256 + jh*128 + wn*32 + j*16 + m16.
  float bv[4];
  #pragma unroll
  for (int jj = 0; jj < 4; ++jj)
    bv[jj] = bias[bn * 256 + (jj >> 1) * 128 + wn * 32 + (jj & 1) * 16 + m16];
  #pragma unroll
  for (int I = 0; I < 8; ++I) {
    const int row0 = bm * 256 + (I >> 2) * 128 + wm * 64 + (I & 3) * 16 + quad * 4;
    #pragma unroll
    for (int jj = 0; jj < 4; ++jj) {
      const int col = bn * 256 + (jj >> 1) * 128 + wn * 32 + (jj & 1) * 16 + m16;
      #pragma unroll
      for (int r = 0; r < 4; ++r)
        out[(size_t)(row0 + r) * DOUT + col] = acc[I][jj][r] + bv[jj];
    }
  }
}

// ---------------------------------------------------------------------------
extern "C" void kernel_launch(void* const* d_in, const int* in_sizes, int n_in,
                              void* d_out, int out_size, void* d_ws, size_t ws_size,
                              hipStream_t stream) {
  const float* x    = (const float*)d_in[0];  // [4,4096,2048]
  const float* mask = (const float*)d_in[1];  // [4,4,4096,1]
  const float* W    = (const float*)d_in[2];  // [2048,2048]
  const float* bias = (const float*)d_in[3];  // [2048]
  const float* A    = (const float*)d_in[4];  // [4,16,2048] -> flat [64,2048]
  const float* Bw   = (const float*)d_in[5];  // [4,2048,16]
  float* out = (float*)d_out;

  // workspace layout:
  //   Xaug  [16384,2112] bf16 = 69,206,016 B
  //   Waug  [ 2048,2112] bf16 =  8,650,752 B
  //   Hpart [4,16384,64] f32  = 16,777,216 B
  // total = 94,633,984 bytes of d_ws
  unsigned short* Xaug = (unsigned short*)d_ws;
  unsigned short* Waug = Xaug + (size_t)M * KA;
  float* Hpart = (float*)(Waug + (size_t)DOUT * KA);

  pass1a_conv_hpart<<<dim3(M / 64 * KSPLIT), dim3(256), 0, stream>>>(x, A, Xaug, Hpart);
  pass1b_reduce_mask<<<dim3(M * 64 / 256), dim3(256), 0, stream>>>(Hpart, mask, Xaug);
  pass2_wcvt<<<dim3((DOUT * (DIN / 8)) / 256), dim3(256), 0, stream>>>(W, Bw, Waug);
  gemm_aug<<<dim3(512), dim3(512), 0, stream>>>(Xaug, Waug, bias, out);
}